// Round 2
// baseline (975.702 us; speedup 1.0000x reference)
//
#include <hip/hip_runtime.h>
#include <stdint.h>

// ---------------------------------------------------------------------------
// SigmoidAttentionJoiner on MI355X (gfx950) — round 1
// M = 40960, J = 512, V = 2000 (pad 2048)
// Changes vs r0: LN folded into q/kv GEMMs (row stats via epilogue atomics),
// K+V merged (N=1024), attention folded into Wo GEMM A-staging (sg scalars),
// BK=64 with XOR-swizzled LDS chunks (kills 16-way b128 bank conflicts).
// ---------------------------------------------------------------------------

typedef __attribute__((ext_vector_type(8))) __bf16 bf16x8;
typedef __attribute__((ext_vector_type(4))) float float4v;
typedef __attribute__((ext_vector_type(8))) unsigned short ushort8;

static constexpr int M_TOT = 16 * 512 * 5;   // 40960
static constexpr int VOUT  = 2000;

#define DI __device__ __forceinline__

DI float bf2f(unsigned short u) {
    union { unsigned int i; float f; } w; w.i = ((unsigned int)u) << 16; return w.f;
}
DI unsigned short f2bf(float f) {
    union { float f; unsigned int i; } w; w.f = f;
    return (unsigned short)((w.i + 0x8000u) >> 16);
}

DI void gld_lds16(const void* g, void* l) {
    __builtin_amdgcn_global_load_lds(
        reinterpret_cast<__attribute__((address_space(1))) void*>(
            reinterpret_cast<uintptr_t>(g)),
        reinterpret_cast<__attribute__((address_space(3))) void*>(
            reinterpret_cast<uintptr_t>(l)),
        16, 0, 0);
}

// ---------------------------------------------------------------------------
// GEMM: C[m,n] = epi( sum_k A[m,k]*B[n,k] )
// EPI 0: proj    — val = acc + bias; store bf16 ld=NOUT; atomic row stats (sum, sumsq)
// EPI 1: lnfold  — val = rstd*acc - rstd*mu*c1[col] + c2[col]; store bf16 ld=NOUT
// EPI 2: tanh    — val = tanh(dres + acc + bias); store bf16 ld=512
// EPI 3: out     — store fp32 ld=NOUT, masked col<NOUT (grid padded)
// ATR 0: A bf16 passthrough (gld_lds); 1: A fp32->bf16 convert; 2: A = v*sg
// LDS chunk swizzle: slot (r, cs) holds global chunk cs^(r&7) — reader XORs back.
// ---------------------------------------------------------------------------
template <int EPI, int NOUT, int ATR, int LDA>
__global__ __launch_bounds__(256) void gemm_bt(
    const void* __restrict__ Ap, const unsigned short* __restrict__ B,
    const float* __restrict__ bias, void* __restrict__ Cp,
    const unsigned short* __restrict__ dres, const float* __restrict__ sgp,
    const float2* __restrict__ stats, float2* __restrict__ statsOut,
    const float* __restrict__ c1, const float* __restrict__ c2)
{
    constexpr int K = 512;
    constexpr int BM = 128, BK = 64;
    __shared__ unsigned short As[BM * BK];
    __shared__ unsigned short Bs[BM * BK];

    const int tid  = threadIdx.x;
    const int wave = tid >> 6;
    const int lane = tid & 63;
    const int wm   = wave >> 1;
    const int wn   = wave & 1;
    const int quad = lane >> 4;
    const int l16  = lane & 15;

    const int m0 = blockIdx.y * BM;
    const int n0 = blockIdx.x * BM;

    float4v acc[4][4];
#pragma unroll
    for (int i = 0; i < 4; i++)
#pragma unroll
        for (int j = 0; j < 4; j++)
            acc[i][j] = {0.f, 0.f, 0.f, 0.f};

    const float*          Af = (const float*)Ap;
    const unsigned short* Ab = (const unsigned short*)Ap;

    for (int k0 = 0; k0 < K; k0 += BK) {
#pragma unroll
        for (int cc = 0; cc < 4; cc++) {
            int s = tid + cc * 256;
            int r = s >> 3, cs = s & 7;
            int gc = cs ^ (r & 7);
            gld_lds16(&B[(size_t)(n0 + r) * K + k0 + gc * 8], &Bs[s * 8]);
        }
        if constexpr (ATR == 0) {
#pragma unroll
            for (int cc = 0; cc < 4; cc++) {
                int s = tid + cc * 256;
                int r = s >> 3, cs = s & 7;
                int gc = cs ^ (r & 7);
                gld_lds16(&Ab[(size_t)(m0 + r) * LDA + k0 + gc * 8], &As[s * 8]);
            }
        } else if constexpr (ATR == 1) {
#pragma unroll
            for (int cc = 0; cc < 4; cc++) {
                int s = tid + cc * 256;
                int r = s >> 3, cs = s & 7;
                int gc = cs ^ (r & 7);
                const float* p = &Af[(size_t)(m0 + r) * LDA + k0 + gc * 8];
                float4 f0 = *(const float4*)p;
                float4 f1 = *(const float4*)(p + 4);
                ushort8 u;
                u[0] = f2bf(f0.x); u[1] = f2bf(f0.y); u[2] = f2bf(f0.z); u[3] = f2bf(f0.w);
                u[4] = f2bf(f1.x); u[5] = f2bf(f1.y); u[6] = f2bf(f1.z); u[7] = f2bf(f1.w);
                *reinterpret_cast<ushort8*>(&As[s * 8]) = u;
            }
        } else {  // ATR == 2: A[row,j] = v[row,j] * sg[row, head]; head uniform = k0>>6
            int head = k0 >> 6;
#pragma unroll
            for (int cc = 0; cc < 4; cc++) {
                int s = tid + cc * 256;
                int r = s >> 3, cs = s & 7;
                int gc = cs ^ (r & 7);
                ushort8 uv = *reinterpret_cast<const ushort8*>(
                    &Ab[(size_t)(m0 + r) * LDA + k0 + gc * 8]);
                float sgv = sgp[(size_t)(m0 + r) * 8 + head];
                ushort8 u;
#pragma unroll
                for (int t = 0; t < 8; t++) u[t] = f2bf(sgv * bf2f(uv[t]));
                *reinterpret_cast<ushort8*>(&As[s * 8]) = u;
            }
        }
        __syncthreads();

#pragma unroll
        for (int h = 0; h < 2; h++) {
            bf16x8 af[4], bv[4];
#pragma unroll
            for (int i = 0; i < 4; i++) {
                int R = wm * 64 + i * 16 + l16;
                int c = h * 4 + quad;
                af[i] = *reinterpret_cast<const bf16x8*>(
                    &As[(R * 8 + (c ^ (R & 7))) * 8]);
            }
#pragma unroll
            for (int j = 0; j < 4; j++) {
                int R = wn * 64 + j * 16 + l16;
                int c = h * 4 + quad;
                bv[j] = *reinterpret_cast<const bf16x8*>(
                    &Bs[(R * 8 + (c ^ (R & 7))) * 8]);
            }
#pragma unroll
            for (int i = 0; i < 4; i++)
#pragma unroll
                for (int j = 0; j < 4; j++)
                    acc[i][j] = __builtin_amdgcn_mfma_f32_16x16x32_bf16(
                        af[i], bv[j], acc[i][j], 0, 0, 0);
        }
        __syncthreads();
    }

    // ---------------- epilogue ----------------
    int colj[4];
    float p0[4], p1[4];
#pragma unroll
    for (int j = 0; j < 4; j++) {
        int col = n0 + wn * 64 + j * 16 + l16;
        colj[j] = col;
        if constexpr (EPI == 1) { p0[j] = c1[col]; p1[j] = c2[col]; }
        else                    { p0[j] = (col < NOUT) ? bias[col] : 0.f; p1[j] = 0.f; }
    }
    unsigned short* C16 = (unsigned short*)Cp;
    float*          Cf  = (float*)Cp;

#pragma unroll
    for (int i = 0; i < 4; i++) {
        int rbase = m0 + wm * 64 + i * 16 + quad * 4;
#pragma unroll
        for (int r = 0; r < 4; r++) {
            int row = rbase + r;
            float mu = 0.f, rstd = 0.f, s = 0.f, ss = 0.f;
            if constexpr (EPI == 1) {
                float2 st = stats[row];
                mu = st.x * (1.f / 512.f);
                float var = st.y * (1.f / 512.f) - mu * mu;
                rstd = rsqrtf(var + 1e-5f);
            }
#pragma unroll
            for (int j = 0; j < 4; j++) {
                float a = acc[i][j][r];
                int col = colj[j];
                if constexpr (EPI == 0) {
                    float val = a + p0[j];
                    C16[(size_t)row * NOUT + col] = f2bf(val);
                    s += val; ss += val * val;
                } else if constexpr (EPI == 1) {
                    float val = rstd * a - rstd * mu * p0[j] + p1[j];
                    C16[(size_t)row * NOUT + col] = f2bf(val);
                } else if constexpr (EPI == 2) {
                    float val = tanhf(bf2f(dres[(size_t)row * 512 + col]) + a + p0[j]);
                    C16[(size_t)row * 512 + col] = f2bf(val);
                } else {
                    if (col < NOUT)
                        Cf[(size_t)row * NOUT + col] = a + p0[j];
                }
            }
            if constexpr (EPI == 0) {
                s  += __shfl_xor(s, 1, 64);  s  += __shfl_xor(s, 2, 64);
                s  += __shfl_xor(s, 4, 64);  s  += __shfl_xor(s, 8, 64);
                ss += __shfl_xor(ss, 1, 64); ss += __shfl_xor(ss, 2, 64);
                ss += __shfl_xor(ss, 4, 64); ss += __shfl_xor(ss, 8, 64);
                if (l16 == 0) {
                    float* sp = (float*)&statsOut[row];
                    atomicAdd(sp + 0, s);
                    atomicAdd(sp + 1, ss);
                }
            }
        }
    }
}

// ---------------------------------------------------------------------------
// weights fp32 -> bf16; Wq folded with g_q, Wk/Wv folded with g_kv; Wout padded
// ---------------------------------------------------------------------------
__global__ __launch_bounds__(256) void wconv_kernel(
    const float* __restrict__ We, const float* __restrict__ Wd,
    const float* __restrict__ Wq, const float* __restrict__ Wk,
    const float* __restrict__ Wv, const float* __restrict__ Wo,
    const float* __restrict__ Wout,
    const float* __restrict__ g_q, const float* __restrict__ g_kv,
    unsigned short* __restrict__ WB)
{
#pragma unroll
    for (int t = 0; t < 4; t++) {
        int i = blockIdx.x * 1024 + t * 256 + threadIdx.x;   // total 2,621,440
        float v;
        if (i < 1572864) {
            int seg = i >> 18, off = i & 262143;
            const float* src = seg == 0 ? We : seg == 1 ? Wd : seg == 2 ? Wq
                             : seg == 3 ? Wk : seg == 4 ? Wv : Wo;
            v = src[off];
            if (seg == 2) v *= g_q[off & 511];
            else if (seg == 3 || seg == 4) v *= g_kv[off & 511];
        } else {
            int rem = i - 1572864;          // Wout region, 2048x512
            int row = rem >> 9;
            v = (row < VOUT) ? Wout[rem] : 0.f;
        }
        WB[i] = f2bf(v);
    }
}

// ---------------------------------------------------------------------------
// prep: c1/c2 for q,k,v (one wave per output row, 1536 rows) + zero stats bufs
// c1[k] = sum_j W[k,j]*g[j];  c2[k] = sum_j W[k,j]*beta[j] + bias[k]
// ---------------------------------------------------------------------------
__global__ __launch_bounds__(256) void prep_kernel(
    const float* __restrict__ Wq, const float* __restrict__ Wk,
    const float* __restrict__ Wv,
    const float* __restrict__ g_q, const float* __restrict__ beta_q,
    const float* __restrict__ g_kv, const float* __restrict__ beta_kv,
    const float* __restrict__ bq, const float* __restrict__ bk,
    const float* __restrict__ bv,
    float* __restrict__ c1q, float* __restrict__ c2q,
    float* __restrict__ c1kv, float* __restrict__ c2kv,
    float* __restrict__ stats_zero)   // 163,840 floats to zero
{
    int b = blockIdx.x;
    if (b < 384) {
        int row  = b * 4 + (threadIdx.x >> 6);  // 0..1535
        int lane = threadIdx.x & 63;
        const float* W  = row < 512 ? Wq : (row < 1024 ? Wk : Wv);
        int wrow        = row < 512 ? row : (row < 1024 ? row - 512 : row - 1024);
        const float* g  = row < 512 ? g_q : g_kv;
        const float* bt = row < 512 ? beta_q : beta_kv;
        float bias      = row < 512 ? bq[row] : (row < 1024 ? bk[row - 512] : bv[row - 1024]);
        float* o1 = row < 512 ? &c1q[row] : &c1kv[row - 512];
        float* o2 = row < 512 ? &c2q[row] : &c2kv[row - 512];
        float s1 = 0.f, s2 = 0.f;
#pragma unroll
        for (int t = 0; t < 8; t++) {
            int j = lane * 8 + t;
            float w = W[(size_t)wrow * 512 + j];
            s1 += w * g[j]; s2 += w * bt[j];
        }
#pragma unroll
        for (int m = 1; m < 64; m <<= 1) {
            s1 += __shfl_xor(s1, m, 64);
            s2 += __shfl_xor(s2, m, 64);
        }
        if (lane == 0) { *o1 = s1; *o2 = s2 + bias; }
    } else {
        int base = (b - 384) * 1024 + threadIdx.x;
#pragma unroll
        for (int t = 0; t < 4; t++) stats_zero[base + t * 256] = 0.f;
    }
}

// ---------------------------------------------------------------------------
// sigmoid scalars: sg[row, h] = sigmoid(dot(q_h, k_h) / 8); one wave per row
// ---------------------------------------------------------------------------
__global__ __launch_bounds__(256) void sg_kernel(
    const unsigned short* __restrict__ q, const unsigned short* __restrict__ kv,
    float* __restrict__ sgbuf)
{
    int row  = blockIdx.x * 4 + (threadIdx.x >> 6);
    int lane = threadIdx.x & 63;
    ushort8 uq = *reinterpret_cast<const ushort8*>(&q[(size_t)row * 512 + lane * 8]);
    ushort8 uk = *reinterpret_cast<const ushort8*>(&kv[(size_t)row * 1024 + lane * 8]);
    float dot = 0.f;
#pragma unroll
    for (int j = 0; j < 8; j++) dot += bf2f(uq[j]) * bf2f(uk[j]);
    dot += __shfl_xor(dot, 1, 64);
    dot += __shfl_xor(dot, 2, 64);
    dot += __shfl_xor(dot, 4, 64);
    if ((lane & 7) == 0)
        sgbuf[(size_t)row * 8 + (lane >> 3)] = 1.f / (1.f + __expf(-dot * 0.125f));
}

// ---------------------------------------------------------------------------
extern "C" void kernel_launch(void* const* d_in, const int* in_sizes, int n_in,
                              void* d_out, int out_size, void* d_ws, size_t ws_size,
                              hipStream_t stream)
{
    (void)in_sizes; (void)n_in; (void)out_size; (void)ws_size;
    const float* enc_in  = (const float*)d_in[0];
    const float* dec_in  = (const float*)d_in[1];
    const float* We      = (const float*)d_in[2];  const float* be     = (const float*)d_in[3];
    const float* Wd      = (const float*)d_in[4];  const float* bd     = (const float*)d_in[5];
    const float* g_q     = (const float*)d_in[6];  const float* beta_q = (const float*)d_in[7];
    const float* g_kv    = (const float*)d_in[8];  const float* beta_kv= (const float*)d_in[9];
    const float* Wq      = (const float*)d_in[10]; const float* bq     = (const float*)d_in[11];
    const float* Wk      = (const float*)d_in[12]; const float* bk     = (const float*)d_in[13];
    const float* Wv      = (const float*)d_in[14]; const float* bv     = (const float*)d_in[15];
    const float* Wo      = (const float*)d_in[16]; const float* bo     = (const float*)d_in[17];
    const float* Wout    = (const float*)d_in[18]; const float* bout   = (const float*)d_in[19];
    float* out = (float*)d_out;

    // --- workspace layout ---
    unsigned short* WB    = (unsigned short*)d_ws;            // 2,621,440 bf16
    unsigned short* WeB   = WB + 0;
    unsigned short* WdB   = WB + 262144;
    unsigned short* WqB   = WB + 524288;     // g-folded
    unsigned short* WkvB  = WB + 786432;     // g-folded, 1024 rows (Wk then Wv)
    unsigned short* WoB   = WB + 1310720;
    unsigned short* WoutB = WB + 1572864;    // 2048 x 512, zero-padded rows

    float* FB = (float*)((char*)d_ws + 5242880);
    float* c1q  = FB;            // 512
    float* c2q  = FB + 512;      // 512
    float* c1kv = FB + 1024;     // 1024
    float* c2kv = FB + 2048;     // 1024
    float2* stats_dec = (float2*)(FB + 3072);       // 40960 float2
    float2* stats_enc = stats_dec + M_TOT;          // 40960 float2
    float*  sgbuf     = FB + 3072 + 4 * M_TOT;      // 40960*8 floats
    float*  stats_zero = FB + 3072;                 // zero both stats arrays

    char* sbase = (char*)d_ws + 7221248;
    const size_t SZ = (size_t)M_TOT * 512 * 2;      // 41,943,040 B
    unsigned short* S0 = (unsigned short*)(sbase + 0 * SZ);  // encO
    unsigned short* S1 = (unsigned short*)(sbase + 1 * SZ);  // decO (live to tanh)
    unsigned short* S2 = (unsigned short*)(sbase + 2 * SZ);  // kv (40960 x 1024)
    unsigned short* S3 = (unsigned short*)(sbase + 4 * SZ);  // h
    unsigned short* S4 = (unsigned short*)(sbase + 5 * SZ);  // q

    dim3 blk(256);
    dim3 g512(4, 320);
    dim3 g1024(8, 320);
    dim3 gout(16, 320);

    wconv_kernel<<<2560, blk, 0, stream>>>(We, Wd, Wq, Wk, Wv, Wo, Wout, g_q, g_kv, WB);
    prep_kernel<<<544, blk, 0, stream>>>(Wq, Wk, Wv, g_q, beta_q, g_kv, beta_kv,
                                         bq, bk, bv, c1q, c2q, c1kv, c2kv, stats_zero);

    // projections (fp32 A -> bf16 staging), with row-stat atomics
    gemm_bt<0, 512, 1, 512><<<g512, blk, 0, stream>>>(
        enc_in, WeB, be, S0, nullptr, nullptr, nullptr, stats_enc, nullptr, nullptr);
    gemm_bt<0, 512, 1, 512><<<g512, blk, 0, stream>>>(
        dec_in, WdB, bd, S1, nullptr, nullptr, nullptr, stats_dec, nullptr, nullptr);

    // q = LNfold(decO) @ Wq^T ; kv = LNfold(encO) @ [Wk;Wv]^T
    gemm_bt<1, 512, 0, 512><<<g512, blk, 0, stream>>>(
        S1, WqB, nullptr, S4, nullptr, nullptr, stats_dec, nullptr, c1q, c2q);
    gemm_bt<1, 1024, 0, 512><<<g1024, blk, 0, stream>>>(
        S0, WkvB, nullptr, S2, nullptr, nullptr, stats_enc, nullptr, c1kv, c2kv);

    // per-(row,head) sigmoid scalars from q and k
    sg_kernel<<<M_TOT / 4, blk, 0, stream>>>(S4, S2, sgbuf);

    // h = tanh(decO + (sg*v) @ Wo^T + bo)
    gemm_bt<2, 512, 2, 1024><<<g512, blk, 0, stream>>>(
        S2 + 512, WoB, bo, S3, S1, sgbuf, nullptr, nullptr, nullptr, nullptr);

    // logits = h @ Wout^T + bout
    gemm_bt<3, 2000, 0, 512><<<gout, blk, 0, stream>>>(
        S3, WoutB, bout, out, nullptr, nullptr, nullptr, nullptr, nullptr, nullptr);
}